// Round 5
// baseline (147.063 us; speedup 1.0000x reference)
//
#include <hip/hip_runtime.h>

#define NUM_VOXELS 2000000
#define NUM_CLUSTS 2000
#define NUM_EDGES  16000

#define ST   2048
#define ACCN (5 * ST)  // 10240 32-bit words = 40 KiB

// Fixed point with +8 bias so both 32-bit halves of a packed u64 stay
// non-negative and never carry across the boundary:
// addend = (v+8)*2^16 <= 14*65536 = 917504; max cluster sum ~1150 voxels
// -> 1.06e9 < 2^31. ds_add_u64 / ds_add_u32 are native (no CAS loop).
#define FSCALE  65536.0f
#define FINV    (1.0f / 65536.0f)
#define BIASF   8.0f
#define BIAS_FS (8.0f * 65536.0f)

// word layout of one accumulator image (ACCN words):
//   [0,4096):    f0 at 2c, f1 at 2c+1   (u64 pair per cluster)
//   [4096,8192): f2 at 2c, f3 at 2c+1
//   [8192,10240): count at c
#define A_BLOCKS  256
#define A_THREADS 1024
#define RED_CH    64   // partials per reduce chunk
#define NCH       (A_BLOCKS / RED_CH)  // 4

typedef float  f4v __attribute__((ext_vector_type(4)));
typedef int    i4v __attribute__((ext_vector_type(4)));
typedef unsigned long long u64;

__device__ __forceinline__ u64 pack2(float a, float b) {
    unsigned lo = (unsigned)__float2int_rn(fmaf(a, FSCALE, BIAS_FS));
    unsigned hi = (unsigned)__float2int_rn(fmaf(b, FSCALE, BIAS_FS));
    return (u64)lo | ((u64)hi << 32);
}

__global__ __launch_bounds__(A_THREADS) void seg_accum(
        const float* __restrict__ data,
        const int* __restrict__ cids,
        int* __restrict__ part) {
    __shared__ __align__(16) int ls[ACCN];
    u64* s01 = (u64*)ls;             // [c] -> words 2c,2c+1
    u64* s23 = (u64*)(ls + 4096);
    int* scnt = ls + 8192;
    for (int o = threadIdx.x; o < ACCN; o += A_THREADS) ls[o] = 0;
    __syncthreads();

    const int ngroups = NUM_VOXELS / 4;  // 4 voxels = 5 float4 + 1 int4 per iter
    for (int g = blockIdx.x * A_THREADS + threadIdx.x; g < ngroups;
         g += gridDim.x * A_THREADS) {
        const f4v* dp = (const f4v*)(data + 20ull * (unsigned)g);
        f4v q0 = __builtin_nontemporal_load(dp + 0);
        f4v q1 = __builtin_nontemporal_load(dp + 1);
        f4v q2 = __builtin_nontemporal_load(dp + 2);
        f4v q3 = __builtin_nontemporal_load(dp + 3);
        f4v q4 = __builtin_nontemporal_load(dp + 4);
        i4v c4 = __builtin_nontemporal_load((const i4v*)(cids + 4ull * (unsigned)g));

        // voxel 0: flat floats 1..4
        atomicAdd(&s01[c4.x], pack2(q0.y, q0.z));
        atomicAdd(&s23[c4.x], pack2(q0.w, q1.x));
        atomicAdd(&scnt[c4.x], 1);
        // voxel 1: flat floats 6..9
        atomicAdd(&s01[c4.y], pack2(q1.z, q1.w));
        atomicAdd(&s23[c4.y], pack2(q2.x, q2.y));
        atomicAdd(&scnt[c4.y], 1);
        // voxel 2: flat floats 11..14
        atomicAdd(&s01[c4.z], pack2(q2.w, q3.x));
        atomicAdd(&s23[c4.z], pack2(q3.y, q3.z));
        atomicAdd(&scnt[c4.z], 1);
        // voxel 3: flat floats 16..19
        atomicAdd(&s01[c4.w], pack2(q4.x, q4.y));
        atomicAdd(&s23[c4.w], pack2(q4.z, q4.w));
        atomicAdd(&scnt[c4.w], 1);
    }
    __syncthreads();

    int* p = part + (size_t)blockIdx.x * ACCN;  // coalesced exact int dump
    for (int o = threadIdx.x; o < ACCN; o += A_THREADS) p[o] = ls[o];
}

// fallback (tiny ws): global int atomics into zeroed chunk 0 of part2
__global__ __launch_bounds__(A_THREADS) void seg_accum_atomic(
        const float* __restrict__ data,
        const int* __restrict__ cids,
        int* __restrict__ acc) {
    __shared__ __align__(16) int ls[ACCN];
    u64* s01 = (u64*)ls;
    u64* s23 = (u64*)(ls + 4096);
    int* scnt = ls + 8192;
    for (int o = threadIdx.x; o < ACCN; o += A_THREADS) ls[o] = 0;
    __syncthreads();
    const int ngroups = NUM_VOXELS / 4;
    for (int g = blockIdx.x * A_THREADS + threadIdx.x; g < ngroups;
         g += gridDim.x * A_THREADS) {
        const f4v* dp = (const f4v*)(data + 20ull * (unsigned)g);
        f4v q0 = dp[0], q1 = dp[1], q2 = dp[2], q3 = dp[3], q4 = dp[4];
        i4v c4 = *(const i4v*)(cids + 4ull * (unsigned)g);
        atomicAdd(&s01[c4.x], pack2(q0.y, q0.z));
        atomicAdd(&s23[c4.x], pack2(q0.w, q1.x));
        atomicAdd(&scnt[c4.x], 1);
        atomicAdd(&s01[c4.y], pack2(q1.z, q1.w));
        atomicAdd(&s23[c4.y], pack2(q2.x, q2.y));
        atomicAdd(&scnt[c4.y], 1);
        atomicAdd(&s01[c4.z], pack2(q2.w, q3.x));
        atomicAdd(&s23[c4.z], pack2(q3.y, q3.z));
        atomicAdd(&scnt[c4.z], 1);
        atomicAdd(&s01[c4.w], pack2(q4.x, q4.y));
        atomicAdd(&s23[c4.w], pack2(q4.z, q4.w));
        atomicAdd(&scnt[c4.w], 1);
    }
    __syncthreads();
    for (int o = threadIdx.x; o < ACCN; o += A_THREADS) {
        int v = ls[o];
        if (v != 0) atomicAdd(&acc[o], v);  // native global_atomic_add_u32
    }
}

// grid dim3(ACCN/256, NCH), block 256. Exact int column sums, no atomics.
__global__ __launch_bounds__(256) void seg_reduce(
        const int* __restrict__ part, int* __restrict__ part2) {
    const int i = blockIdx.x * 256 + threadIdx.x;
    const int* p = part + (size_t)blockIdx.y * RED_CH * ACCN + i;
    int s0 = 0, s1 = 0, s2 = 0, s3 = 0;
#pragma unroll
    for (int b = 0; b < RED_CH; b += 4) {
        s0 += p[(size_t)(b + 0) * ACCN];
        s1 += p[(size_t)(b + 1) * ACCN];
        s2 += p[(size_t)(b + 2) * ACCN];
        s3 += p[(size_t)(b + 3) * ACCN];
    }
    part2[(size_t)blockIdx.y * ACCN + i] = (s0 + s1) + (s2 + s3);
}

#define E_BLOCKS 256
#define E_THREADS 256
#define E_WAVES (E_BLOCKS * (E_THREADS / 64))

__global__ __launch_bounds__(E_THREADS) void edge_mlp(
        const int* __restrict__ part2,  // NCH chunk images, summed here
        const int* __restrict__ eidx,
        const float* __restrict__ W1, const float* __restrict__ b1,
        const float* __restrict__ W2, const float* __restrict__ b2,
        float* __restrict__ out) {
    __shared__ float sacc[ACCN];                 // 40 KiB accumulator image
    __shared__ float hbuf[E_THREADS / 64][128];  // per-wave h exchange
    const int lane = threadIdx.x & 63;
    const int w = threadIdx.x >> 6;
    const int wg = blockIdx.x * (E_THREADS / 64) + w;

    float w1a[4], w1b[4];
#pragma unroll
    for (int c = 0; c < 4; ++c) {
        w1a[c] = W1[c * 128 + lane];
        w1b[c] = W1[c * 128 + 64 + lane];
    }
    const float b1a = b1[lane];
    const float b1b = b1[64 + lane];
    const float b2j = b2[lane];
    float w2c[128];  // W2 column `lane` (fully-unrolled static indexing, no spill)
#pragma unroll
    for (int k = 0; k < 128; ++k) w2c[k] = W2[k * 64 + lane];

    // stage: sum NCH exact int chunks, convert (features keep +8 bias;
    // removed per-edge below). Branch uniform: 8192 % 256 == 0.
    for (int o = threadIdx.x; o < ACCN; o += E_THREADS) {
        int s = part2[o] + part2[ACCN + o] + part2[2 * ACCN + o] +
                part2[3 * ACCN + o];
        sacc[o] = (o < 8192) ? (float)s * FINV : (float)s;
    }
    __syncthreads();

    int e0 = 0, e1 = 0;
    if (wg < NUM_EDGES) {
        e0 = eidx[wg];
        e1 = eidx[NUM_EDGES + wg];
    }
    for (int e = wg; e < NUM_EDGES; e += E_WAVES) {
        // prefetch next edge's ids (hide global-load latency behind compute)
        const int ne = e + E_WAVES;
        int n0 = 0, n1 = 0;
        if (ne < NUM_EDGES) {
            n0 = eidx[ne];
            n1 = eidx[NUM_EDGES + ne];
        }
        const float cnt = sacc[8192 + e0] + sacc[8192 + e1];
        const float rden = 1.0f / fmaxf(cnt, 1.0f);
        const float bterm = BIASF * cnt;  // unbias: r_f = S_f + 8*cnt
        const float r0 = sacc[2 * e0] + sacc[2 * e1];
        const float r1 = sacc[2 * e0 + 1] + sacc[2 * e1 + 1];
        const float r2 = sacc[4096 + 2 * e0] + sacc[4096 + 2 * e1];
        const float r3 = sacc[4096 + 2 * e0 + 1] + sacc[4096 + 2 * e1 + 1];
        const float p0 = (r0 - bterm) * rden;
        const float p1 = (r1 - bterm) * rden;
        const float p2 = (r2 - bterm) * rden;
        const float p3 = (r3 - bterm) * rden;

        float ha = b1a + p0 * w1a[0] + p1 * w1a[1] + p2 * w1a[2] + p3 * w1a[3];
        float hb = b1b + p0 * w1b[0] + p1 * w1b[1] + p2 * w1b[2] + p3 * w1b[3];
        ha = fmaxf(ha, 0.0f);
        hb = fmaxf(hb, 0.0f);

        hbuf[w][lane] = ha;
        hbuf[w][64 + lane] = hb;

        float a0 = b2j, a1 = 0.f, a2 = 0.f, a3 = 0.f;  // 4-way ILP
#pragma unroll
        for (int k = 0; k < 128; k += 16) {
            float4 h4;
            h4 = *(const float4*)&hbuf[w][k];
            a0 += h4.x * w2c[k] + h4.y * w2c[k + 1] + h4.z * w2c[k + 2] + h4.w * w2c[k + 3];
            h4 = *(const float4*)&hbuf[w][k + 4];
            a1 += h4.x * w2c[k + 4] + h4.y * w2c[k + 5] + h4.z * w2c[k + 6] + h4.w * w2c[k + 7];
            h4 = *(const float4*)&hbuf[w][k + 8];
            a2 += h4.x * w2c[k + 8] + h4.y * w2c[k + 9] + h4.z * w2c[k + 10] + h4.w * w2c[k + 11];
            h4 = *(const float4*)&hbuf[w][k + 12];
            a3 += h4.x * w2c[k + 12] + h4.y * w2c[k + 13] + h4.z * w2c[k + 14] + h4.w * w2c[k + 15];
        }
        out[(size_t)e * 64 + lane] = (a0 + a1) + (a2 + a3);
        e0 = n0;
        e1 = n1;
    }
}

extern "C" void kernel_launch(void* const* d_in, const int* in_sizes, int n_in,
                              void* d_out, int out_size, void* d_ws, size_t ws_size,
                              hipStream_t stream) {
    const float* data = (const float*)d_in[0];
    const int* cids   = (const int*)d_in[1];
    const int* eidx   = (const int*)d_in[2];
    const float* W1   = (const float*)d_in[3];
    const float* b1   = (const float*)d_in[4];
    const float* W2   = (const float*)d_in[5];
    const float* b2   = (const float*)d_in[6];
    float* out = (float*)d_out;
    int* ws = (int*)d_ws;

    if (ws_size >= (size_t)(A_BLOCKS + NCH) * ACCN * sizeof(int)) {
        int* part  = ws;
        int* part2 = ws + (size_t)A_BLOCKS * ACCN;
        seg_accum<<<A_BLOCKS, A_THREADS, 0, stream>>>(data, cids, part);
        seg_reduce<<<dim3(ACCN / 256, NCH), 256, 0, stream>>>(part, part2);
        edge_mlp<<<E_BLOCKS, E_THREADS, 0, stream>>>(part2, eidx, W1, b1, W2, b2, out);
    } else {
        int* part2 = ws;  // NCH*ACCN ints = 160 KiB; chunks 1..3 stay zero
        hipMemsetAsync(part2, 0, (size_t)NCH * ACCN * sizeof(int), stream);
        seg_accum_atomic<<<A_BLOCKS, A_THREADS, 0, stream>>>(data, cids, part2);
        edge_mlp<<<E_BLOCKS, E_THREADS, 0, stream>>>(part2, eidx, W1, b1, W2, b2, out);
    }
}

// Round 6
// 125.784 us; speedup vs baseline: 1.1692x; 1.1692x over previous
//
#include <hip/hip_runtime.h>

#define NUM_VOXELS 2000000
#define NUM_CLUSTS 2000
#define NUM_EDGES  16000

#define ST   2048
#define ACCN (5 * ST)  // 10240 32-bit words = 40 KiB per accumulator image

// Fixed point with +8 bias so both 32-bit halves of a packed u64 stay
// non-negative and never carry across the boundary:
// addend = (v+8)*2^16 <= ~14*65536; max cluster sum ~1150*14*2^16 ~= 1.06e9 < 2^31.
// ds_add_u64 / ds_add_u32 are native (float LDS atomicAdd = CAS loop -> 100x slow).
#define FSCALE  65536.0f
#define FINV    (1.0f / 65536.0f)
#define BIASF   8.0f
#define BIAS_FS (8.0f * 65536.0f)

// word layout of one accumulator image (ACCN words):
//   [0,4096):     f0 at 2c, f1 at 2c+1   (u64 pair per cluster)
//   [4096,8192):  f2 at 2c, f3 at 2c+1
//   [8192,10240): count at c
#define A_BLOCKS  512   // 2 blocks/CU (R4-proven occupancy; 256 was a regression risk)
#define A_THREADS 1024
#define RED_CH    64    // partials per reduce chunk
#define NCH       (A_BLOCKS / RED_CH)  // 8

typedef float  f4v __attribute__((ext_vector_type(4)));
typedef int    i4v __attribute__((ext_vector_type(4)));
typedef unsigned long long u64;

__device__ __forceinline__ u64 pack2(float a, float b) {
    unsigned lo = (unsigned)__float2int_rn(fmaf(a, FSCALE, BIAS_FS));
    unsigned hi = (unsigned)__float2int_rn(fmaf(b, FSCALE, BIAS_FS));
    return (u64)lo | ((u64)hi << 32);
}

__global__ __launch_bounds__(A_THREADS) void seg_accum(
        const float* __restrict__ data,
        const int* __restrict__ cids,
        int* __restrict__ part) {
    __shared__ __align__(16) int ls[ACCN];
    u64* s01 = (u64*)ls;             // [c] -> words 2c,2c+1
    u64* s23 = (u64*)(ls + 4096);
    int* scnt = ls + 8192;
    for (int o = threadIdx.x; o < ACCN; o += A_THREADS) ls[o] = 0;
    __syncthreads();

    const int ngroups = NUM_VOXELS / 4;  // 4 voxels = 5 float4 + 1 int4 per iter
    for (int g = blockIdx.x * A_THREADS + threadIdx.x; g < ngroups;
         g += gridDim.x * A_THREADS) {
        const f4v* dp = (const f4v*)(data + 20ull * (unsigned)g);
        f4v q0 = __builtin_nontemporal_load(dp + 0);
        f4v q1 = __builtin_nontemporal_load(dp + 1);
        f4v q2 = __builtin_nontemporal_load(dp + 2);
        f4v q3 = __builtin_nontemporal_load(dp + 3);
        f4v q4 = __builtin_nontemporal_load(dp + 4);
        i4v c4 = __builtin_nontemporal_load((const i4v*)(cids + 4ull * (unsigned)g));

        atomicAdd(&s01[c4.x], pack2(q0.y, q0.z));
        atomicAdd(&s23[c4.x], pack2(q0.w, q1.x));
        atomicAdd(&scnt[c4.x], 1);
        atomicAdd(&s01[c4.y], pack2(q1.z, q1.w));
        atomicAdd(&s23[c4.y], pack2(q2.x, q2.y));
        atomicAdd(&scnt[c4.y], 1);
        atomicAdd(&s01[c4.z], pack2(q2.w, q3.x));
        atomicAdd(&s23[c4.z], pack2(q3.y, q3.z));
        atomicAdd(&scnt[c4.z], 1);
        atomicAdd(&s01[c4.w], pack2(q4.x, q4.y));
        atomicAdd(&s23[c4.w], pack2(q4.z, q4.w));
        atomicAdd(&scnt[c4.w], 1);
    }
    __syncthreads();

    int* p = part + (size_t)blockIdx.x * ACCN;  // coalesced exact int dump
    for (int o = threadIdx.x; o < ACCN; o += A_THREADS) p[o] = ls[o];
}

// fallback (tiny ws): native global u32 atomic flush into one zeroed image
__global__ __launch_bounds__(A_THREADS) void seg_accum_atomic(
        const float* __restrict__ data,
        const int* __restrict__ cids,
        int* __restrict__ acc) {
    __shared__ __align__(16) int ls[ACCN];
    u64* s01 = (u64*)ls;
    u64* s23 = (u64*)(ls + 4096);
    int* scnt = ls + 8192;
    for (int o = threadIdx.x; o < ACCN; o += A_THREADS) ls[o] = 0;
    __syncthreads();
    const int ngroups = NUM_VOXELS / 4;
    for (int g = blockIdx.x * A_THREADS + threadIdx.x; g < ngroups;
         g += gridDim.x * A_THREADS) {
        const f4v* dp = (const f4v*)(data + 20ull * (unsigned)g);
        f4v q0 = dp[0], q1 = dp[1], q2 = dp[2], q3 = dp[3], q4 = dp[4];
        i4v c4 = *(const i4v*)(cids + 4ull * (unsigned)g);
        atomicAdd(&s01[c4.x], pack2(q0.y, q0.z));
        atomicAdd(&s23[c4.x], pack2(q0.w, q1.x));
        atomicAdd(&scnt[c4.x], 1);
        atomicAdd(&s01[c4.y], pack2(q1.z, q1.w));
        atomicAdd(&s23[c4.y], pack2(q2.x, q2.y));
        atomicAdd(&scnt[c4.y], 1);
        atomicAdd(&s01[c4.z], pack2(q2.w, q3.x));
        atomicAdd(&s23[c4.z], pack2(q3.y, q3.z));
        atomicAdd(&scnt[c4.z], 1);
        atomicAdd(&s01[c4.w], pack2(q4.x, q4.y));
        atomicAdd(&s23[c4.w], pack2(q4.z, q4.w));
        atomicAdd(&scnt[c4.w], 1);
    }
    __syncthreads();
    for (int o = threadIdx.x; o < ACCN; o += A_THREADS) {
        int v = ls[o];
        if (v != 0) atomicAdd(&acc[o], v);
    }
}

// grid dim3(ACCN/256, NCH), block 256: exact int column sums, no atomics.
__global__ __launch_bounds__(256) void seg_reduce(
        const int* __restrict__ part, int* __restrict__ part2) {
    const int i = blockIdx.x * 256 + threadIdx.x;
    const int* p = part + (size_t)blockIdx.y * RED_CH * ACCN + i;
    int s0 = 0, s1 = 0, s2 = 0, s3 = 0;
#pragma unroll
    for (int b = 0; b < RED_CH; b += 4) {
        s0 += p[(size_t)(b + 0) * ACCN];
        s1 += p[(size_t)(b + 1) * ACCN];
        s2 += p[(size_t)(b + 2) * ACCN];
        s3 += p[(size_t)(b + 3) * ACCN];
    }
    part2[(size_t)blockIdx.y * ACCN + i] = (s0 + s1) + (s2 + s3);
}

// sum nch chunk images -> finalized float cluster table (64 KiB, L2-resident):
// clustf[c*8 + {0..3}] = un-biased float feature sums, [c*8+4] = count.
__global__ __launch_bounds__(256) void clust_final(
        const int* __restrict__ part2, float* __restrict__ clustf, int nch) {
    const int c = blockIdx.x * 256 + threadIdx.x;
    if (c >= NUM_CLUSTS) return;
    int s0 = 0, s1 = 0, s2 = 0, s3 = 0, cn = 0;
    for (int ch = 0; ch < nch; ++ch) {
        const int* p = part2 + (size_t)ch * ACCN;
        s0 += p[2 * c];
        s1 += p[2 * c + 1];
        s2 += p[4096 + 2 * c];
        s3 += p[4096 + 2 * c + 1];
        cn += p[8192 + c];
    }
    const float fc = (float)cn;
    float4 v;
    v.x = fmaf((float)s0, FINV, -BIASF * fc);
    v.y = fmaf((float)s1, FINV, -BIASF * fc);
    v.z = fmaf((float)s2, FINV, -BIASF * fc);
    v.w = fmaf((float)s3, FINV, -BIASF * fc);
    *(float4*)&clustf[c * 8] = v;
    clustf[c * 8 + 4] = fc;
}

#define E_BLOCKS 500   // 500 blocks x 4 waves x 8 edges = 16000 exactly
#define E_THREADS 256
#define EPW 8

__global__ __launch_bounds__(E_THREADS) void edge_mlp(
        const float* __restrict__ clustf,
        const int* __restrict__ eidx,
        const float* __restrict__ W1, const float* __restrict__ b1,
        const float* __restrict__ W2, const float* __restrict__ b2,
        float* __restrict__ out) {
    __shared__ float hbuf[E_THREADS / 64][2][128];  // double-buffered h exchange
    const int lane = threadIdx.x & 63;
    const int w = threadIdx.x >> 6;
    const int wg = blockIdx.x * (E_THREADS / 64) + w;  // 0..1999
    const int ebase = wg * EPW;

    float w1a[4], w1b[4];
#pragma unroll
    for (int c = 0; c < 4; ++c) {
        w1a[c] = W1[c * 128 + lane];
        w1b[c] = W1[c * 128 + 64 + lane];
    }
    const float b1a = b1[lane];
    const float b1b = b1[64 + lane];
    const float b2j = b2[lane];
    float w2c[128];  // W2 column `lane` (unified VGPR/AGPR file holds it)
#pragma unroll
    for (int k = 0; k < 128; ++k) w2c[k] = W2[k * 64 + lane];

    // broadcast-load this wave's 8 edge id pairs (same addr all lanes -> 1 line)
    int ids0[EPW], ids1[EPW];
    {
        i4v a = *(const i4v*)&eidx[ebase];
        i4v b = *(const i4v*)&eidx[ebase + 4];
        ids0[0] = a.x; ids0[1] = a.y; ids0[2] = a.z; ids0[3] = a.w;
        ids0[4] = b.x; ids0[5] = b.y; ids0[6] = b.z; ids0[7] = b.w;
        i4v c = *(const i4v*)&eidx[NUM_EDGES + ebase];
        i4v d = *(const i4v*)&eidx[NUM_EDGES + ebase + 4];
        ids1[0] = c.x; ids1[1] = c.y; ids1[2] = c.z; ids1[3] = c.w;
        ids1[4] = d.x; ids1[5] = d.y; ids1[6] = d.z; ids1[7] = d.w;
    }

#pragma unroll
    for (int i = 0; i < EPW; ++i) {
        const int e0 = ids0[i], e1 = ids1[i];
        const float4 sa = *(const float4*)&clustf[e0 * 8];  // broadcast L2 hit
        const float  ca = clustf[e0 * 8 + 4];
        const float4 sb = *(const float4*)&clustf[e1 * 8];
        const float  cb = clustf[e1 * 8 + 4];
        const float rden = 1.0f / fmaxf(ca + cb, 1.0f);
        const float p0 = (sa.x + sb.x) * rden;
        const float p1 = (sa.y + sb.y) * rden;
        const float p2 = (sa.z + sb.z) * rden;
        const float p3 = (sa.w + sb.w) * rden;

        float ha = b1a + p0 * w1a[0] + p1 * w1a[1] + p2 * w1a[2] + p3 * w1a[3];
        float hb = b1b + p0 * w1b[0] + p1 * w1b[1] + p2 * w1b[2] + p3 * w1b[3];
        ha = fmaxf(ha, 0.0f);
        hb = fmaxf(hb, 0.0f);

        float* hx = hbuf[w][i & 1];  // double buffer: iter i+1 writes overlap iter i reads
        hx[lane] = ha;
        hx[64 + lane] = hb;

        float a0 = b2j, a1 = 0.f, a2 = 0.f, a3 = 0.f;
#pragma unroll
        for (int k = 0; k < 128; k += 16) {
            float4 h4;
            h4 = *(const float4*)&hx[k];
            a0 += h4.x * w2c[k] + h4.y * w2c[k + 1] + h4.z * w2c[k + 2] + h4.w * w2c[k + 3];
            h4 = *(const float4*)&hx[k + 4];
            a1 += h4.x * w2c[k + 4] + h4.y * w2c[k + 5] + h4.z * w2c[k + 6] + h4.w * w2c[k + 7];
            h4 = *(const float4*)&hx[k + 8];
            a2 += h4.x * w2c[k + 8] + h4.y * w2c[k + 9] + h4.z * w2c[k + 10] + h4.w * w2c[k + 11];
            h4 = *(const float4*)&hx[k + 12];
            a3 += h4.x * w2c[k + 12] + h4.y * w2c[k + 13] + h4.z * w2c[k + 14] + h4.w * w2c[k + 15];
        }
        out[(size_t)(ebase + i) * 64 + lane] = (a0 + a1) + (a2 + a3);
    }
}

extern "C" void kernel_launch(void* const* d_in, const int* in_sizes, int n_in,
                              void* d_out, int out_size, void* d_ws, size_t ws_size,
                              hipStream_t stream) {
    const float* data = (const float*)d_in[0];
    const int* cids   = (const int*)d_in[1];
    const int* eidx   = (const int*)d_in[2];
    const float* W1   = (const float*)d_in[3];
    const float* b1   = (const float*)d_in[4];
    const float* W2   = (const float*)d_in[5];
    const float* b2   = (const float*)d_in[6];
    float* out = (float*)d_out;
    int* ws = (int*)d_ws;

    const size_t full_need =
        ((size_t)A_BLOCKS + NCH) * ACCN * sizeof(int) + NUM_CLUSTS * 8 * sizeof(float);
    if (ws_size >= full_need) {
        int* part  = ws;
        int* part2 = ws + (size_t)A_BLOCKS * ACCN;
        float* clustf = (float*)(ws + (size_t)(A_BLOCKS + NCH) * ACCN);
        seg_accum<<<A_BLOCKS, A_THREADS, 0, stream>>>(data, cids, part);
        seg_reduce<<<dim3(ACCN / 256, NCH), 256, 0, stream>>>(part, part2);
        clust_final<<<(NUM_CLUSTS + 255) / 256, 256, 0, stream>>>(part2, clustf, NCH);
        edge_mlp<<<E_BLOCKS, E_THREADS, 0, stream>>>(clustf, eidx, W1, b1, W2, b2, out);
    } else {
        int* img = ws;  // one 40 KiB image
        float* clustf = (float*)(ws + ACCN);
        hipMemsetAsync(img, 0, ACCN * sizeof(int), stream);
        seg_accum_atomic<<<A_BLOCKS, A_THREADS, 0, stream>>>(data, cids, img);
        clust_final<<<(NUM_CLUSTS + 255) / 256, 256, 0, stream>>>(img, clustf, 1);
        edge_mlp<<<E_BLOCKS, E_THREADS, 0, stream>>>(clustf, eidx, W1, b1, W2, b2, out);
    }
}

// Round 7
// 117.931 us; speedup vs baseline: 1.2470x; 1.0666x over previous
//
#include <hip/hip_runtime.h>

#define NUM_VOXELS 2000000
#define NUM_CLUSTS 2000
#define NUM_EDGES  16000

#define ST   2048
#define ACCN (5 * ST)  // 10240 32-bit words = 40 KiB per accumulator image

// Fixed point with +8 bias so both 32-bit halves of a packed u64 stay
// non-negative and never carry across the boundary:
// addend = (v+8)*2^16 <= ~14*65536; max cluster sum ~1150*14*2^16 ~= 1.0e9 < 2^31.
// ds_add_u64 / ds_add_u32 are native (float LDS atomicAdd = CAS loop -> 100x slow).
#define FSCALE  65536.0f
#define FINV    (1.0f / 65536.0f)
#define BIASF   8.0f
#define BIAS_FS (8.0f * 65536.0f)

// word layout of one accumulator image (ACCN words):
//   [0,4096):     f0 at 2c, f1 at 2c+1   (u64 pair per cluster)
//   [4096,8192):  f2 at 2c, f3 at 2c+1
//   [8192,10240): count at c
#define A_BLOCKS  256   // R4-measured-fast config: 1 block/CU, 10.5 MB partials
#define A_THREADS 1024
#define RED_CH    64
#define NCH       (A_BLOCKS / RED_CH)  // 4

typedef float  f4v __attribute__((ext_vector_type(4)));
typedef int    i4v __attribute__((ext_vector_type(4)));
typedef unsigned long long u64;

__device__ __forceinline__ u64 pack2(float a, float b) {
    unsigned lo = (unsigned)__float2int_rn(fmaf(a, FSCALE, BIAS_FS));
    unsigned hi = (unsigned)__float2int_rn(fmaf(b, FSCALE, BIAS_FS));
    return (u64)lo | ((u64)hi << 32);
}

__global__ __launch_bounds__(A_THREADS) void seg_accum(
        const float* __restrict__ data,
        const int* __restrict__ cids,
        int* __restrict__ part) {
    __shared__ __align__(16) int ls[ACCN];
    u64* s01 = (u64*)ls;             // [c] -> words 2c,2c+1
    u64* s23 = (u64*)(ls + 4096);
    int* scnt = ls + 8192;
    for (int o = threadIdx.x; o < ACCN; o += A_THREADS) ls[o] = 0;
    __syncthreads();

    const int ngroups = NUM_VOXELS / 4;  // 4 voxels = 5 float4 + 1 int4 per iter
    for (int g = blockIdx.x * A_THREADS + threadIdx.x; g < ngroups;
         g += gridDim.x * A_THREADS) {
        const f4v* dp = (const f4v*)(data + 20ull * (unsigned)g);
        f4v q0 = dp[0];
        f4v q1 = dp[1];
        f4v q2 = dp[2];
        f4v q3 = dp[3];
        f4v q4 = dp[4];
        i4v c4 = *(const i4v*)(cids + 4ull * (unsigned)g);

        atomicAdd(&s01[c4.x], pack2(q0.y, q0.z));
        atomicAdd(&s23[c4.x], pack2(q0.w, q1.x));
        atomicAdd(&scnt[c4.x], 1);
        atomicAdd(&s01[c4.y], pack2(q1.z, q1.w));
        atomicAdd(&s23[c4.y], pack2(q2.x, q2.y));
        atomicAdd(&scnt[c4.y], 1);
        atomicAdd(&s01[c4.z], pack2(q2.w, q3.x));
        atomicAdd(&s23[c4.z], pack2(q3.y, q3.z));
        atomicAdd(&scnt[c4.z], 1);
        atomicAdd(&s01[c4.w], pack2(q4.x, q4.y));
        atomicAdd(&s23[c4.w], pack2(q4.z, q4.w));
        atomicAdd(&scnt[c4.w], 1);
    }
    __syncthreads();

    int* p = part + (size_t)blockIdx.x * ACCN;  // coalesced exact int dump
    for (int o = threadIdx.x; o < ACCN; o += A_THREADS) p[o] = ls[o];
}

// fallback (tiny ws): native global u32 atomic flush into one zeroed image
__global__ __launch_bounds__(A_THREADS) void seg_accum_atomic(
        const float* __restrict__ data,
        const int* __restrict__ cids,
        int* __restrict__ acc) {
    __shared__ __align__(16) int ls[ACCN];
    u64* s01 = (u64*)ls;
    u64* s23 = (u64*)(ls + 4096);
    int* scnt = ls + 8192;
    for (int o = threadIdx.x; o < ACCN; o += A_THREADS) ls[o] = 0;
    __syncthreads();
    const int ngroups = NUM_VOXELS / 4;
    for (int g = blockIdx.x * A_THREADS + threadIdx.x; g < ngroups;
         g += gridDim.x * A_THREADS) {
        const f4v* dp = (const f4v*)(data + 20ull * (unsigned)g);
        f4v q0 = dp[0], q1 = dp[1], q2 = dp[2], q3 = dp[3], q4 = dp[4];
        i4v c4 = *(const i4v*)(cids + 4ull * (unsigned)g);
        atomicAdd(&s01[c4.x], pack2(q0.y, q0.z));
        atomicAdd(&s23[c4.x], pack2(q0.w, q1.x));
        atomicAdd(&scnt[c4.x], 1);
        atomicAdd(&s01[c4.y], pack2(q1.z, q1.w));
        atomicAdd(&s23[c4.y], pack2(q2.x, q2.y));
        atomicAdd(&scnt[c4.y], 1);
        atomicAdd(&s01[c4.z], pack2(q2.w, q3.x));
        atomicAdd(&s23[c4.z], pack2(q3.y, q3.z));
        atomicAdd(&scnt[c4.z], 1);
        atomicAdd(&s01[c4.w], pack2(q4.x, q4.y));
        atomicAdd(&s23[c4.w], pack2(q4.z, q4.w));
        atomicAdd(&scnt[c4.w], 1);
    }
    __syncthreads();
    for (int o = threadIdx.x; o < ACCN; o += A_THREADS) {
        int v = ls[o];
        if (v != 0) atomicAdd(&acc[o], v);
    }
}

// grid dim3(ACCN/256, NCH), block 256. Sums its chunk of partials and
// atomically folds into partial image 0 (the final image) — no zeroing
// needed since image 0 already holds block 0's exact contribution.
// y==0 skips partial 0 (it's the destination/base).
__global__ __launch_bounds__(256) void seg_combine(int* __restrict__ part) {
    const int i = blockIdx.x * 256 + threadIdx.x;
    const int b0 = blockIdx.y * RED_CH + (blockIdx.y == 0 ? 1 : 0);
    const int b1 = blockIdx.y * RED_CH + RED_CH;
    int s = 0;
    for (int b = b0; b < b1; ++b) s += part[(size_t)b * ACCN + i];
    atomicAdd(&part[i], s);  // native global_atomic_add_u32, 4 per element total
}

#define E_BLOCKS 500   // 500 blocks x 4 waves x 8 edges = 16000 exactly
#define E_THREADS 256
#define EPW 8

__global__ __launch_bounds__(E_THREADS) void edge_mlp(
        const int* __restrict__ img,   // finalized int accumulator image
        const int* __restrict__ eidx,
        const float* __restrict__ W1, const float* __restrict__ b1,
        const float* __restrict__ W2, const float* __restrict__ b2,
        float* __restrict__ out) {
    __shared__ float hbuf[E_THREADS / 64][2][128];  // double-buffered h exchange
    const int lane = threadIdx.x & 63;
    const int w = threadIdx.x >> 6;
    const int wg = blockIdx.x * (E_THREADS / 64) + w;  // 0..1999
    const int ebase = wg * EPW;

    float w1a[4], w1b[4];
#pragma unroll
    for (int c = 0; c < 4; ++c) {
        w1a[c] = W1[c * 128 + lane];
        w1b[c] = W1[c * 128 + 64 + lane];
    }
    const float b1a = b1[lane];
    const float b1b = b1[64 + lane];
    const float b2j = b2[lane];
    float w2c[128];  // W2 column `lane` in registers
#pragma unroll
    for (int k = 0; k < 128; ++k) w2c[k] = W2[k * 64 + lane];

    // broadcast-load this wave's 8 edge id pairs (same addr all lanes)
    int ids0[EPW], ids1[EPW];
    {
        i4v a = *(const i4v*)&eidx[ebase];
        i4v b = *(const i4v*)&eidx[ebase + 4];
        ids0[0] = a.x; ids0[1] = a.y; ids0[2] = a.z; ids0[3] = a.w;
        ids0[4] = b.x; ids0[5] = b.y; ids0[6] = b.z; ids0[7] = b.w;
        i4v c = *(const i4v*)&eidx[NUM_EDGES + ebase];
        i4v d = *(const i4v*)&eidx[NUM_EDGES + ebase + 4];
        ids1[0] = c.x; ids1[1] = c.y; ids1[2] = c.z; ids1[3] = c.w;
        ids1[4] = d.x; ids1[5] = d.y; ids1[6] = d.z; ids1[7] = d.w;
    }

#pragma unroll
    for (int i = 0; i < EPW; ++i) {
        const int e0 = ids0[i], e1 = ids1[i];
        // broadcast int loads from the 40 KiB L2-resident image
        const i4v fa = {img[2 * e0], img[2 * e0 + 1],
                        img[4096 + 2 * e0], img[4096 + 2 * e0 + 1]};
        const i4v fb = {img[2 * e1], img[2 * e1 + 1],
                        img[4096 + 2 * e1], img[4096 + 2 * e1 + 1]};
        const float cnt = (float)img[8192 + e0] + (float)img[8192 + e1];
        const float rden = 1.0f / fmaxf(cnt, 1.0f);
        const float bt = -BIASF * cnt;
        // convert each cluster's sum separately (avoids int32 overflow on add)
        const float p0 = fmaf((float)fa.x + (float)fb.x, FINV, bt) * rden;
        const float p1 = fmaf((float)fa.y + (float)fb.y, FINV, bt) * rden;
        const float p2 = fmaf((float)fa.z + (float)fb.z, FINV, bt) * rden;
        const float p3 = fmaf((float)fa.w + (float)fb.w, FINV, bt) * rden;

        float ha = b1a + p0 * w1a[0] + p1 * w1a[1] + p2 * w1a[2] + p3 * w1a[3];
        float hb = b1b + p0 * w1b[0] + p1 * w1b[1] + p2 * w1b[2] + p3 * w1b[3];
        ha = fmaxf(ha, 0.0f);
        hb = fmaxf(hb, 0.0f);

        float* hx = hbuf[w][i & 1];  // double buffer across iterations
        hx[lane] = ha;
        hx[64 + lane] = hb;

        float a0 = b2j, a1 = 0.f, a2 = 0.f, a3 = 0.f;
#pragma unroll
        for (int k = 0; k < 128; k += 16) {
            float4 h4;
            h4 = *(const float4*)&hx[k];
            a0 += h4.x * w2c[k] + h4.y * w2c[k + 1] + h4.z * w2c[k + 2] + h4.w * w2c[k + 3];
            h4 = *(const float4*)&hx[k + 4];
            a1 += h4.x * w2c[k + 4] + h4.y * w2c[k + 5] + h4.z * w2c[k + 6] + h4.w * w2c[k + 7];
            h4 = *(const float4*)&hx[k + 8];
            a2 += h4.x * w2c[k + 8] + h4.y * w2c[k + 9] + h4.z * w2c[k + 10] + h4.w * w2c[k + 11];
            h4 = *(const float4*)&hx[k + 12];
            a3 += h4.x * w2c[k + 12] + h4.y * w2c[k + 13] + h4.z * w2c[k + 14] + h4.w * w2c[k + 15];
        }
        out[(size_t)(ebase + i) * 64 + lane] = (a0 + a1) + (a2 + a3);
    }
}

extern "C" void kernel_launch(void* const* d_in, const int* in_sizes, int n_in,
                              void* d_out, int out_size, void* d_ws, size_t ws_size,
                              hipStream_t stream) {
    const float* data = (const float*)d_in[0];
    const int* cids   = (const int*)d_in[1];
    const int* eidx   = (const int*)d_in[2];
    const float* W1   = (const float*)d_in[3];
    const float* b1   = (const float*)d_in[4];
    const float* W2   = (const float*)d_in[5];
    const float* b2   = (const float*)d_in[6];
    float* out = (float*)d_out;
    int* ws = (int*)d_ws;

    if (ws_size >= (size_t)A_BLOCKS * ACCN * sizeof(int)) {
        int* part = ws;  // image 0 doubles as the final accumulator image
        seg_accum<<<A_BLOCKS, A_THREADS, 0, stream>>>(data, cids, part);
        seg_combine<<<dim3(ACCN / 256, NCH), 256, 0, stream>>>(part);
        edge_mlp<<<E_BLOCKS, E_THREADS, 0, stream>>>(part, eidx, W1, b1, W2, b2, out);
    } else {
        int* img = ws;  // one 40 KiB image
        hipMemsetAsync(img, 0, ACCN * sizeof(int), stream);
        seg_accum_atomic<<<A_BLOCKS, A_THREADS, 0, stream>>>(data, cids, img);
        edge_mlp<<<E_BLOCKS, E_THREADS, 0, stream>>>(img, eidx, W1, b1, W2, b2, out);
    }
}